// Round 7
// baseline (360.843 us; speedup 1.0000x reference)
//
#include <hip/hip_runtime.h>
#include <hip/hip_bf16.h>

typedef __attribute__((ext_vector_type(8))) short bf16x8;
typedef __attribute__((ext_vector_type(4))) float f32x4;
typedef __hip_bfloat16 bf16;
typedef unsigned long long ull;

#define BATCH 8
#define SEQ   2048
#define DMODEL 512
#define DHEAD 64
#define ROWS (BATCH * SEQ)
#define SCALE_LOG2 0.1803368801f   // (1/8) * log2(e)

static __device__ inline short f2bf(float f) {
    union { __hip_bfloat16 h; short s; } u;
    u.h = __float2bfloat16(f);
    return u.s;
}

// ---------------------------------------------------------------------------
// W transpose: w[512][64] fp32 -> wt[64][512] bf16. grid 24, block 256.
__global__ __launch_bounds__(256) void transpose_w_kernel(
    const float* __restrict__ wq, const float* __restrict__ wk,
    const float* __restrict__ wv, bf16* __restrict__ wt)
{
    const int s  = blockIdx.x / 8;
    const int kt = blockIdx.x % 8;
    const float* w = (s == 0) ? wq : ((s == 1) ? wk : wv);

    __shared__ float Ts[64][68];

    const int tid = threadIdx.x;
    int nr = tid >> 4;
    int n4 = (tid & 15) * 4;
#pragma unroll
    for (int p = 0; p < 4; ++p) {
        int k = 16 * p + nr;
        float4 v = *(const float4*)(w + (size_t)(kt * 64 + k) * DHEAD + n4);
        Ts[k][n4] = v.x; Ts[k][n4 + 1] = v.y; Ts[k][n4 + 2] = v.z; Ts[k][n4 + 3] = v.w;
    }
    __syncthreads();
#pragma unroll
    for (int p = 0; p < 2; ++p) {
        int cc = tid + p * 256;
        int n = cc >> 3;
        int kk = (cc & 7) * 8;
        bf16x8 o;
#pragma unroll
        for (int e = 0; e < 8; ++e) o[e] = f2bf(Ts[kk + e][n]);
        *(bf16x8*)(wt + (size_t)(s * 64 + n) * DMODEL + kt * 64 + kk) = o;
    }
}

// ---------------------------------------------------------------------------
// PREP: merged proj (compute-bound) + mask-pack (HBM-bound) so the 134 MB
// mask stream overlaps the projection MFMA work. grid 2048, block 256.
// role = (bid>>3)&1 keeps XCD round-robin (bid&7) balanced per role.
__global__ __launch_bounds__(256) void prep_kernel(
    const float* __restrict__ x, const bf16* __restrict__ wt,
    const int* __restrict__ mask,
    bf16* __restrict__ Q, bf16* __restrict__ K, bf16* __restrict__ Vt,
    ull* __restrict__ pm)
{
    const int bid = blockIdx.x;
    const int role = (bid >> 3) & 1;
    const int sub = ((bid >> 4) << 3) | (bid & 7);   // 0..1023
    const int tid = threadIdx.x;

    __shared__ __align__(8) bf16 Vs[64][20];

    if (role == 1) {
        // ----- mask pack: 1024 blocks x 4 waves, 32 chunks/wave -----
        const int wgl = sub * 4 + (tid >> 6);        // 0..4095
        const int lane = tid & 63;
        const uint4* src = (const uint4*)mask;       // index: chunk*64 + lane
        const size_t cbase = (size_t)wgl * 32;

        for (int it = 0; it < 8; ++it) {
            size_t c0 = cbase + it * 4;
            uint4 v0 = src[(c0 + 0) * 64 + lane];
            uint4 v1 = src[(c0 + 1) * 64 + lane];
            uint4 v2 = src[(c0 + 2) * 64 + lane];
            uint4 v3 = src[(c0 + 3) * 64 + lane];
            ull b00 = __ballot(v0.x != 0), b01 = __ballot(v0.y != 0);
            ull b02 = __ballot(v0.z != 0), b03 = __ballot(v0.w != 0);
            ull b10 = __ballot(v1.x != 0), b11 = __ballot(v1.y != 0);
            ull b12 = __ballot(v1.z != 0), b13 = __ballot(v1.w != 0);
            ull b20 = __ballot(v2.x != 0), b21 = __ballot(v2.y != 0);
            ull b22 = __ballot(v2.z != 0), b23 = __ballot(v2.w != 0);
            ull b30 = __ballot(v3.x != 0), b31 = __ballot(v3.y != 0);
            ull b32 = __ballot(v3.z != 0), b33 = __ballot(v3.w != 0);
            if (lane == 0) {
                ull* d = pm + c0 * 4;
                d[0]  = b00; d[1]  = b01; d[2]  = b02; d[3]  = b03;
                d[4]  = b10; d[5]  = b11; d[6]  = b12; d[7]  = b13;
                d[8]  = b20; d[9]  = b21; d[10] = b22; d[11] = b23;
                d[12] = b30; d[13] = b31; d[14] = b32; d[15] = b33;
            }
        }
        return;
    }

    // ----- fused QKV projection: 1024 blocks, 16 rows each -----
    const int bb = sub & 7;                 // batch -> XCD pin
    const int tt = sub >> 3;                // 0..127 tile within batch
    const int r0 = bb * SEQ + tt * 16;
    const int lane = tid & 63;
    const int cq = tid >> 6;                // 0..3 col quarter
    const int l15 = lane & 15;
    const int quad = lane >> 4;

    f32x4 acc[3] = {};

    const float* xp = x + (size_t)(r0 + l15) * DMODEL + quad * 8;

#pragma unroll
    for (int k0 = 0; k0 < DMODEL; k0 += 64) {
        float4 xa = *(const float4*)(xp + k0);
        float4 xb = *(const float4*)(xp + k0 + 4);
        float4 xc = *(const float4*)(xp + k0 + 32);
        float4 xd = *(const float4*)(xp + k0 + 36);
        bf16x8 a0, a1;
        a0[0] = f2bf(xa.x); a0[1] = f2bf(xa.y); a0[2] = f2bf(xa.z); a0[3] = f2bf(xa.w);
        a0[4] = f2bf(xb.x); a0[5] = f2bf(xb.y); a0[6] = f2bf(xb.z); a0[7] = f2bf(xb.w);
        a1[0] = f2bf(xc.x); a1[1] = f2bf(xc.y); a1[2] = f2bf(xc.z); a1[3] = f2bf(xc.w);
        a1[4] = f2bf(xd.x); a1[5] = f2bf(xd.y); a1[6] = f2bf(xd.z); a1[7] = f2bf(xd.w);

#pragma unroll
        for (int g = 0; g < 3; ++g) {
            int n = 16 * (3 * cq + g) + l15;
            const bf16* wp = wt + (size_t)n * DMODEL + k0 + quad * 8;
            bf16x8 b0 = *(const bf16x8*)(wp);
            bf16x8 b1 = *(const bf16x8*)(wp + 32);
            acc[g] = __builtin_amdgcn_mfma_f32_16x16x32_bf16(a0, b0, acc[g], 0, 0, 0);
            acc[g] = __builtin_amdgcn_mfma_f32_16x16x32_bf16(a1, b1, acc[g], 0, 0, 0);
        }
    }

#pragma unroll
    for (int g = 0; g < 3; ++g) {
        int ng = 16 * (3 * cq + g) + l15;   // 0..191
        int sel = ng >> 6;
        int col = ng & 63;
#pragma unroll
        for (int r = 0; r < 4; ++r) {
            int rowl = quad * 4 + r;            // 0..15
            int row = r0 + rowl;
            union { __hip_bfloat16 h; bf16 b; } u;
            u.h = __float2bfloat16(acc[g][r]);
            if (sel == 0)      Q[(size_t)row * DHEAD + col] = u.b;
            else if (sel == 1) K[(size_t)row * DHEAD + col] = u.b;
            else               Vs[col][rowl] = u.b;
        }
    }
    __syncthreads();

    {   // coalesced Vt store: 256 thr x 8B = 64 d-rows x 16 j
        int d = tid >> 2;
        int j4 = (tid & 3) * 4;
        uint2 payload = *(const uint2*)(&Vs[d][j4]);
        *(uint2*)(Vt + ((size_t)(bb * DHEAD + d)) * SEQ + tt * 16 + j4) = payload;
    }
}

// ---------------------------------------------------------------------------
// Flash attention, 8-way j-split. grid (BATCH, SEQ/16), block 512 (8 waves).
// Each wave owns 256 j => the whole mask for a row is ONE ull, preloaded as
// 4 SSA scalars (no arrays, no spill, zero in-loop mask memory). Ps and Om
// share one 32 KB LDS region (Ps dead after the loop) -> 33 KB total ->
// 4 blocks/CU = 32 waves/CU.
__global__ __launch_bounds__(512, 8) void flash_kernel(
    const bf16* __restrict__ Q, const bf16* __restrict__ K,
    const bf16* __restrict__ Vt, const ull* __restrict__ pm,
    float* __restrict__ out)
{
    const int b = blockIdx.x;          // batch (XCD-pinned)
    const int q0 = blockIdx.y * 16;
    const int tid = threadIdx.x;
    const int lane = tid & 63;
    const int wid = tid >> 6;          // j-split 0..7
    const int l15 = lane & 15;
    const int quad = lane >> 4;

    __shared__ __align__(16) unsigned char smem[8 * 16 * 64 * 4];   // 32 KB union
    bf16  (*Ps)[16][72] = (bf16 (*)[16][72])smem;    // 18.4 KB used in-loop
    float (*Om)[16][64] = (float(*)[16][64])smem;    // 32 KB used post-loop
    __shared__ float Lw[8][16];

    // one packed-mask ull per row for this wave's 256-j range
    const int sh = l15 >> 2;
    const size_t rb = (size_t)(b * SEQ + q0 + quad * 4);
    ull w0 = pm[((rb + 0) * 8 + wid) * 4 + (l15 & 3)] >> sh;
    ull w1 = pm[((rb + 1) * 8 + wid) * 4 + (l15 & 3)] >> sh;
    ull w2 = pm[((rb + 2) * 8 + wid) * 4 + (l15 & 3)] >> sh;
    ull w3 = pm[((rb + 3) * 8 + wid) * 4 + (l15 & 3)] >> sh;

    const bf16* qp = Q + ((size_t)(b * SEQ + q0 + l15)) * DHEAD + quad * 8;
    bf16x8 aQ0 = *(const bf16x8*)(qp);
    bf16x8 aQ1 = *(const bf16x8*)(qp + 32);

    f32x4 oacc[4] = {};
    float lsum[4] = {0.f, 0.f, 0.f, 0.f};

    const int jbase = wid * 256;

#pragma unroll
    for (int jt = 0; jt < 4; ++jt) {
        const int j0 = jbase + jt * 64;

        // S = Q K^T
        f32x4 sacc[4] = {};
#pragma unroll
        for (int c = 0; c < 4; ++c) {
            const bf16* kp = K + ((size_t)(b * SEQ + j0 + 16 * c + l15)) * DHEAD + quad * 8;
            bf16x8 b0 = *(const bf16x8*)(kp);
            bf16x8 b1 = *(const bf16x8*)(kp + 32);
            sacc[c] = __builtin_amdgcn_mfma_f32_16x16x32_bf16(aQ0, b0, sacc[c], 0, 0, 0);
            sacc[c] = __builtin_amdgcn_mfma_f32_16x16x32_bf16(aQ1, b1, sacc[c], 0, 0, 0);
        }

        // p = maskbit ? exp(s/8) : 0, store to wave-private Ps (no barrier)
#pragma unroll
        for (int c = 0; c < 4; ++c) {
            const int bit = 16 * jt + 4 * c;
            {
                float e = exp2f(sacc[c][0] * SCALE_LOG2);
                float p = ((w0 >> bit) & 1ull) ? e : 0.0f;
                lsum[0] += p;
                union { __hip_bfloat16 h; bf16 b; } u; u.h = __float2bfloat16(p);
                Ps[wid][quad * 4 + 0][16 * c + l15] = u.b;
            }
            {
                float e = exp2f(sacc[c][1] * SCALE_LOG2);
                float p = ((w1 >> bit) & 1ull) ? e : 0.0f;
                lsum[1] += p;
                union { __hip_bfloat16 h; bf16 b; } u; u.h = __float2bfloat16(p);
                Ps[wid][quad * 4 + 1][16 * c + l15] = u.b;
            }
            {
                float e = exp2f(sacc[c][2] * SCALE_LOG2);
                float p = ((w2 >> bit) & 1ull) ? e : 0.0f;
                lsum[2] += p;
                union { __hip_bfloat16 h; bf16 b; } u; u.h = __float2bfloat16(p);
                Ps[wid][quad * 4 + 2][16 * c + l15] = u.b;
            }
            {
                float e = exp2f(sacc[c][3] * SCALE_LOG2);
                float p = ((w3 >> bit) & 1ull) ? e : 0.0f;
                lsum[3] += p;
                union { __hip_bfloat16 h; bf16 b; } u; u.h = __float2bfloat16(p);
                Ps[wid][quad * 4 + 3][16 * c + l15] = u.b;
            }
        }

        bf16x8 aP0 = *(const bf16x8*)(&Ps[wid][l15][quad * 8]);
        bf16x8 aP1 = *(const bf16x8*)(&Ps[wid][l15][32 + quad * 8]);
#pragma unroll
        for (int c = 0; c < 4; ++c) {
            const bf16* vp = Vt + ((size_t)b * DHEAD + 16 * c + l15) * SEQ + j0 + quad * 8;
            bf16x8 v0 = *(const bf16x8*)(vp);
            bf16x8 v1 = *(const bf16x8*)(vp + 32);
            oacc[c] = __builtin_amdgcn_mfma_f32_16x16x32_bf16(aP0, v0, oacc[c], 0, 0, 0);
            oacc[c] = __builtin_amdgcn_mfma_f32_16x16x32_bf16(aP1, v1, oacc[c], 0, 0, 0);
        }
    }

    __syncthreads();   // all waves done with Ps before smem becomes Om

#pragma unroll
    for (int r = 0; r < 4; ++r) {
        lsum[r] += __shfl_xor(lsum[r], 1);
        lsum[r] += __shfl_xor(lsum[r], 2);
        lsum[r] += __shfl_xor(lsum[r], 4);
        lsum[r] += __shfl_xor(lsum[r], 8);
    }

#pragma unroll
    for (int c = 0; c < 4; ++c)
#pragma unroll
        for (int r = 0; r < 4; ++r)
            Om[wid][quad * 4 + r][16 * c + l15] = oacc[c][r];
    if (l15 == 0) {
#pragma unroll
        for (int r = 0; r < 4; ++r) Lw[wid][quad * 4 + r] = lsum[r];
    }
    __syncthreads();

    {   // combine: 16 rows x 64 cols, 512 threads x float2
        int row = tid >> 5;
        int c0 = (tid & 31) * 2;
        float L = Lw[0][row] + Lw[1][row] + Lw[2][row] + Lw[3][row] +
                  Lw[4][row] + Lw[5][row] + Lw[6][row] + Lw[7][row];
        float invL = 1.0f / L;
        float2 o;
        float* op = (float*)&o;
#pragma unroll
        for (int e = 0; e < 2; ++e) {
            float s = 0.f;
#pragma unroll
            for (int k = 0; k < 8; ++k) s += Om[k][row][c0 + e];
            op[e] = s * invL;
        }
        *(float2*)(out + ((size_t)(b * SEQ + q0 + row)) * DHEAD + c0) = o;
    }
}

extern "C" void kernel_launch(void* const* d_in, const int* in_sizes, int n_in,
                              void* d_out, int out_size, void* d_ws, size_t ws_size,
                              hipStream_t stream)
{
    // setup_inputs order: mask, x_key_value, wk, wq, wv   (wk BEFORE wq!)
    const int*   mask = (const int*)d_in[0];
    const float* x    = (const float*)d_in[1];
    const float* wk   = (const float*)d_in[2];
    const float* wq   = (const float*)d_in[3];
    const float* wv   = (const float*)d_in[4];
    float* out = (float*)d_out;

    bf16* Qb = (bf16*)d_ws;
    bf16* Kb = Qb + (size_t)ROWS * DHEAD;
    bf16* Vt = Kb + (size_t)ROWS * DHEAD;
    bf16* Wt = Vt + (size_t)BATCH * DHEAD * SEQ;
    ull*  pm = (ull*)(Wt + 3 * 64 * DMODEL);   // 8B-aligned

    transpose_w_kernel<<<dim3(24), 256, 0, stream>>>(wq, wk, wv, Wt);
    prep_kernel<<<dim3(2048), 256, 0, stream>>>(x, Wt, mask, Qb, Kb, Vt, pm);
    flash_kernel<<<dim3(BATCH, SEQ / 16), 512, 0, stream>>>(Qb, Kb, Vt, pm, out);
}

// Round 8
// 340.638 us; speedup vs baseline: 1.0593x; 1.0593x over previous
//
#include <hip/hip_runtime.h>
#include <hip/hip_bf16.h>

typedef __attribute__((ext_vector_type(8))) short bf16x8;
typedef __attribute__((ext_vector_type(4))) float f32x4;
typedef __attribute__((ext_vector_type(4))) _Float16 f16x4;
typedef __hip_bfloat16 bf16;
typedef unsigned long long ull;
typedef __attribute__((ext_vector_type(2))) ull ullx2;

#define BATCH 8
#define SEQ   2048
#define DMODEL 512
#define DHEAD 64
#define ROWS (BATCH * SEQ)
#define SCALE_LOG2 0.1803368801f   // (1/8) * log2(e)

static __device__ inline short f2bf(float f) {
    union { __hip_bfloat16 h; short s; } u;
    u.h = __float2bfloat16(f);
    return u.s;
}

// ---------------------------------------------------------------------------
// W transpose: w[512][64] fp32 -> wt[64][512] bf16. grid 24, block 256.
__global__ __launch_bounds__(256) void transpose_w_kernel(
    const float* __restrict__ wq, const float* __restrict__ wk,
    const float* __restrict__ wv, bf16* __restrict__ wt)
{
    const int s  = blockIdx.x / 8;
    const int kt = blockIdx.x % 8;
    const float* w = (s == 0) ? wq : ((s == 1) ? wk : wv);

    __shared__ float Ts[64][68];

    const int tid = threadIdx.x;
    int nr = tid >> 4;
    int n4 = (tid & 15) * 4;
#pragma unroll
    for (int p = 0; p < 4; ++p) {
        int k = 16 * p + nr;
        float4 v = *(const float4*)(w + (size_t)(kt * 64 + k) * DHEAD + n4);
        Ts[k][n4] = v.x; Ts[k][n4 + 1] = v.y; Ts[k][n4 + 2] = v.z; Ts[k][n4 + 3] = v.w;
    }
    __syncthreads();
#pragma unroll
    for (int p = 0; p < 2; ++p) {
        int cc = tid + p * 256;
        int n = cc >> 3;
        int kk = (cc & 7) * 8;
        bf16x8 o;
#pragma unroll
        for (int e = 0; e < 8; ++e) o[e] = f2bf(Ts[kk + e][n]);
        *(bf16x8*)(wt + (size_t)(s * 64 + n) * DMODEL + kt * 64 + kk) = o;
    }
}

// ---------------------------------------------------------------------------
// PREP: merged proj (compute-bound) + mask-pack (HBM-bound) so the 134 MB
// mask stream overlaps the projection MFMA work. grid 2048, block 256.
// V is emitted transposed AND in fp16 (PV MFMA runs in f16).
__global__ __launch_bounds__(256) void prep_kernel(
    const float* __restrict__ x, const bf16* __restrict__ wt,
    const int* __restrict__ mask,
    bf16* __restrict__ Q, bf16* __restrict__ K, _Float16* __restrict__ Vt,
    ull* __restrict__ pm)
{
    const int bid = blockIdx.x;
    const int role = (bid >> 3) & 1;
    const int sub = ((bid >> 4) << 3) | (bid & 7);   // 0..1023
    const int tid = threadIdx.x;

    __shared__ __align__(8) _Float16 Vs[64][20];

    if (role == 1) {
        // ----- mask pack: 1024 blocks x 4 waves, 32 chunks/wave -----
        const int wgl = sub * 4 + (tid >> 6);        // 0..4095
        const int lane = tid & 63;
        const uint4* src = (const uint4*)mask;       // index: chunk*64 + lane
        const size_t cbase = (size_t)wgl * 32;

        for (int it = 0; it < 8; ++it) {
            size_t c0 = cbase + it * 4;
            uint4 v0 = src[(c0 + 0) * 64 + lane];
            uint4 v1 = src[(c0 + 1) * 64 + lane];
            uint4 v2 = src[(c0 + 2) * 64 + lane];
            uint4 v3 = src[(c0 + 3) * 64 + lane];
            ull b00 = __ballot(v0.x != 0), b01 = __ballot(v0.y != 0);
            ull b02 = __ballot(v0.z != 0), b03 = __ballot(v0.w != 0);
            ull b10 = __ballot(v1.x != 0), b11 = __ballot(v1.y != 0);
            ull b12 = __ballot(v1.z != 0), b13 = __ballot(v1.w != 0);
            ull b20 = __ballot(v2.x != 0), b21 = __ballot(v2.y != 0);
            ull b22 = __ballot(v2.z != 0), b23 = __ballot(v2.w != 0);
            ull b30 = __ballot(v3.x != 0), b31 = __ballot(v3.y != 0);
            ull b32 = __ballot(v3.z != 0), b33 = __ballot(v3.w != 0);
            if (lane == 0) {
                ull* d = pm + c0 * 4;
                d[0]  = b00; d[1]  = b01; d[2]  = b02; d[3]  = b03;
                d[4]  = b10; d[5]  = b11; d[6]  = b12; d[7]  = b13;
                d[8]  = b20; d[9]  = b21; d[10] = b22; d[11] = b23;
                d[12] = b30; d[13] = b31; d[14] = b32; d[15] = b33;
            }
        }
        return;
    }

    // ----- fused QKV projection: 1024 blocks, 16 rows each -----
    const int bb = sub & 7;                 // batch -> XCD pin
    const int tt = sub >> 3;                // 0..127 tile within batch
    const int r0 = bb * SEQ + tt * 16;
    const int lane = tid & 63;
    const int cq = tid >> 6;                // 0..3 col quarter
    const int l15 = lane & 15;
    const int quad = lane >> 4;

    f32x4 acc[3] = {};

    const float* xp = x + (size_t)(r0 + l15) * DMODEL + quad * 8;

#pragma unroll
    for (int k0 = 0; k0 < DMODEL; k0 += 64) {
        float4 xa = *(const float4*)(xp + k0);
        float4 xb = *(const float4*)(xp + k0 + 4);
        float4 xc = *(const float4*)(xp + k0 + 32);
        float4 xd = *(const float4*)(xp + k0 + 36);
        bf16x8 a0, a1;
        a0[0] = f2bf(xa.x); a0[1] = f2bf(xa.y); a0[2] = f2bf(xa.z); a0[3] = f2bf(xa.w);
        a0[4] = f2bf(xb.x); a0[5] = f2bf(xb.y); a0[6] = f2bf(xb.z); a0[7] = f2bf(xb.w);
        a1[0] = f2bf(xc.x); a1[1] = f2bf(xc.y); a1[2] = f2bf(xc.z); a1[3] = f2bf(xc.w);
        a1[4] = f2bf(xd.x); a1[5] = f2bf(xd.y); a1[6] = f2bf(xd.z); a1[7] = f2bf(xd.w);

#pragma unroll
        for (int g = 0; g < 3; ++g) {
            int n = 16 * (3 * cq + g) + l15;
            const bf16* wp = wt + (size_t)n * DMODEL + k0 + quad * 8;
            bf16x8 b0 = *(const bf16x8*)(wp);
            bf16x8 b1 = *(const bf16x8*)(wp + 32);
            acc[g] = __builtin_amdgcn_mfma_f32_16x16x32_bf16(a0, b0, acc[g], 0, 0, 0);
            acc[g] = __builtin_amdgcn_mfma_f32_16x16x32_bf16(a1, b1, acc[g], 0, 0, 0);
        }
    }

#pragma unroll
    for (int g = 0; g < 3; ++g) {
        int ng = 16 * (3 * cq + g) + l15;   // 0..191
        int sel = ng >> 6;
        int col = ng & 63;
#pragma unroll
        for (int r = 0; r < 4; ++r) {
            int rowl = quad * 4 + r;            // 0..15
            int row = r0 + rowl;
            if (sel == 0) {
                union { __hip_bfloat16 h; bf16 b; } u;
                u.h = __float2bfloat16(acc[g][r]);
                Q[(size_t)row * DHEAD + col] = u.b;
            } else if (sel == 1) {
                union { __hip_bfloat16 h; bf16 b; } u;
                u.h = __float2bfloat16(acc[g][r]);
                K[(size_t)row * DHEAD + col] = u.b;
            } else {
                Vs[col][rowl] = (_Float16)acc[g][r];
            }
        }
    }
    __syncthreads();

    {   // coalesced Vt store: 256 thr x 8B = 64 d-rows x 16 j
        int d = tid >> 2;
        int j4 = (tid & 3) * 4;
        uint2 payload = *(const uint2*)(&Vs[d][j4]);
        *(uint2*)(Vt + ((size_t)(bb * DHEAD + d)) * SEQ + tt * 16 + j4) = payload;
    }
}

// ---------------------------------------------------------------------------
// Flash attention, S^T formulation. grid (BATCH, SEQ/16), block 512 (8 waves,
// 8-way j-split x 256). S^T = K·Q^T puts scores in a layout that IS the
// A-operand layout of mfma_f32_16x16x16f16 — P·V needs no LDS and no lane
// permutes. Mask: lane l15 = query row, so each lane preloads its row's
// 256-bit chunk as 4 SSA ulls (word r covers j%4==r). No arrays -> no spill.
__global__ __launch_bounds__(512, 4) void flash_kernel(
    const bf16* __restrict__ Q, const bf16* __restrict__ K,
    const _Float16* __restrict__ Vt, const ull* __restrict__ pm,
    float* __restrict__ out)
{
    const int b = blockIdx.x;          // batch (XCD-pinned)
    const int q0 = blockIdx.y * 16;
    const int tid = threadIdx.x;
    const int lane = tid & 63;
    const int wid = tid >> 6;          // j-split 0..7
    const int l15 = lane & 15;
    const int quad = lane >> 4;

    __shared__ float Om[8][16][64];    // 32 KB, used only post-loop
    __shared__ float Lw[8][16];

    // mask words: this lane's query row (i = l15), this wave's 256-j chunk.
    // word r: bit (16*jt + 4*c + quad) = mask[i][wid*256 + 64*jt + 16*c + quad*4 + r]
    const ull* pmp = pm + ((size_t)(b * SEQ + q0 + l15) * 8 + wid) * 4;
    ullx2 m01 = *(const ullx2*)(pmp);
    ullx2 m23 = *(const ullx2*)(pmp + 2);
    const ull mw0 = m01.x, mw1 = m01.y, mw2 = m23.x, mw3 = m23.y;

    // Q rows as B-operand (n = i = l15, k = quad*8+e)
    const bf16* qp = Q + ((size_t)(b * SEQ + q0 + l15)) * DHEAD + quad * 8;
    bf16x8 bQ0 = *(const bf16x8*)(qp);
    bf16x8 bQ1 = *(const bf16x8*)(qp + 32);

    f32x4 oacc[4] = {};
    float ls0 = 0.f, ls1 = 0.f, ls2 = 0.f, ls3 = 0.f;

    const int jbase = wid * 256;

#pragma unroll
    for (int jt = 0; jt < 4; ++jt) {
        const int j0 = jbase + jt * 64;

        // S^T = K · Q^T  (K rows as A: m = j = l15; C: col=l15=i, row=quad*4+r=j)
        f32x4 sacc[4] = {};
#pragma unroll
        for (int c = 0; c < 4; ++c) {
            const bf16* kp = K + ((size_t)(b * SEQ + j0 + 16 * c + l15)) * DHEAD + quad * 8;
            bf16x8 kf0 = *(const bf16x8*)(kp);
            bf16x8 kf1 = *(const bf16x8*)(kp + 32);
            sacc[c] = __builtin_amdgcn_mfma_f32_16x16x32_bf16(kf0, bQ0, sacc[c], 0, 0, 0);
            sacc[c] = __builtin_amdgcn_mfma_f32_16x16x32_bf16(kf1, bQ1, sacc[c], 0, 0, 0);
        }

#pragma unroll
        for (int c = 0; c < 4; ++c) {
            const int sh = 16 * jt + 4 * c + quad;
            float e0 = exp2f(sacc[c][0] * SCALE_LOG2);
            float e1 = exp2f(sacc[c][1] * SCALE_LOG2);
            float e2 = exp2f(sacc[c][2] * SCALE_LOG2);
            float e3 = exp2f(sacc[c][3] * SCALE_LOG2);
            float p0 = ((mw0 >> sh) & 1ull) ? e0 : 0.0f;
            float p1 = ((mw1 >> sh) & 1ull) ? e1 : 0.0f;
            float p2 = ((mw2 >> sh) & 1ull) ? e2 : 0.0f;
            float p3 = ((mw3 >> sh) & 1ull) ? e3 : 0.0f;
            if (c == 0) ls0 += (p0 + p1) + (p2 + p3);
            else if (c == 1) ls1 += (p0 + p1) + (p2 + p3);
            else if (c == 2) ls2 += (p0 + p1) + (p2 + p3);
            else ls3 += (p0 + p1) + (p2 + p3);

            // P fragment IS the A-operand of the K=16 MFMA (m=i=l15, k=quad*4+r)
            f16x4 pf;
            pf[0] = (_Float16)p0; pf[1] = (_Float16)p1;
            pf[2] = (_Float16)p2; pf[3] = (_Float16)p3;

#pragma unroll
            for (int g = 0; g < 4; ++g) {
                f16x4 vf = *(const f16x4*)(Vt + ((size_t)(b * DHEAD + 16 * g + l15)) * SEQ
                                               + j0 + 16 * c + quad * 4);
                oacc[g] = __builtin_amdgcn_mfma_f32_16x16x16f16(pf, vf, oacc[g], 0, 0, 0);
            }
        }
    }

    // lane's partial row-sum belongs to row i = l15; reduce across quads
    float lsum = (ls0 + ls1) + (ls2 + ls3);
    lsum += __shfl_xor(lsum, 16);
    lsum += __shfl_xor(lsum, 32);

    // stash partials: O C-layout row = quad*4+r = i, col = 16g+l15 = d
#pragma unroll
    for (int g = 0; g < 4; ++g)
#pragma unroll
        for (int r = 0; r < 4; ++r)
            Om[wid][quad * 4 + r][16 * g + l15] = oacc[g][r];
    if (quad == 0) Lw[wid][l15] = lsum;
    __syncthreads();

    {   // combine: 16 rows x 64 cols, 512 threads x float2
        int row = tid >> 5;
        int c0 = (tid & 31) * 2;
        float L = Lw[0][row] + Lw[1][row] + Lw[2][row] + Lw[3][row] +
                  Lw[4][row] + Lw[5][row] + Lw[6][row] + Lw[7][row];
        float invL = 1.0f / L;
        float2 o;
        float* op = (float*)&o;
#pragma unroll
        for (int e = 0; e < 2; ++e) {
            float s = 0.f;
#pragma unroll
            for (int k = 0; k < 8; ++k) s += Om[k][row][c0 + e];
            op[e] = s * invL;
        }
        *(float2*)(out + ((size_t)(b * SEQ + q0 + row)) * DHEAD + c0) = o;
    }
}

extern "C" void kernel_launch(void* const* d_in, const int* in_sizes, int n_in,
                              void* d_out, int out_size, void* d_ws, size_t ws_size,
                              hipStream_t stream)
{
    // setup_inputs order: mask, x_key_value, wk, wq, wv   (wk BEFORE wq!)
    const int*   mask = (const int*)d_in[0];
    const float* x    = (const float*)d_in[1];
    const float* wk   = (const float*)d_in[2];
    const float* wq   = (const float*)d_in[3];
    const float* wv   = (const float*)d_in[4];
    float* out = (float*)d_out;

    bf16*      Qb = (bf16*)d_ws;
    bf16*      Kb = Qb + (size_t)ROWS * DHEAD;
    _Float16*  Vt = (_Float16*)(Kb + (size_t)ROWS * DHEAD);
    bf16*      Wt = (bf16*)(Vt + (size_t)BATCH * DHEAD * SEQ);
    ull*       pm = (ull*)(Wt + 3 * 64 * DMODEL);   // 8B-aligned

    transpose_w_kernel<<<dim3(24), 256, 0, stream>>>(wq, wk, wv, Wt);
    prep_kernel<<<dim3(2048), 256, 0, stream>>>(x, Wt, mask, Qb, Kb, Vt, pm);
    flash_kernel<<<dim3(BATCH, SEQ / 16), 512, 0, stream>>>(Qb, Kb, Vt, pm, out);
}